// Round 1
// 209.845 us; speedup vs baseline: 1.0636x; 1.0636x over previous
//
#include <hip/hip_runtime.h>
#include <math.h>

#define N_NODES 100000
#define N_EDGES 3200000
#define D_FEAT 128
#define H1 32
#define H2 16
#define NC 8

#define NBUCK 391          // buckets of 256 dst nodes: ceil(100000/256)
#define BCAP 16384         // fixed ebuf slots per bucket
#define EPB 4096           // edges per k_bscatter block (32 KB LDS -> 4 blocks/CU)
#define EPT 8              // edges per thread (EPB / 512)

typedef short s16x8 __attribute__((ext_vector_type(8)));
typedef float f32x4 __attribute__((ext_vector_type(4)));

// bf16 helpers (round-to-nearest-even pack, shift-expand)
__device__ inline unsigned short f2bf(float f) {
    unsigned int u = __float_as_uint(f);
    u += 0x7FFF + ((u >> 16) & 1);
    return (unsigned short)(u >> 16);
}
__device__ inline float bf2f(unsigned short h) {
    return __uint_as_float((unsigned int)h << 16);
}

// ---------------- detect edge dtype + zero cursors + W1 B-fragment prep ------

__global__ void k_detect(const int* __restrict__ ei, const float* __restrict__ W1,
                         int* __restrict__ meta, int* __restrict__ bucket_cursor,
                         unsigned short* __restrict__ W1f) {
    __shared__ int red[256];
    int v = 0;
    for (int i = threadIdx.x; i < 1024; i += 256) v |= ei[2 * i + 1];
    red[threadIdx.x] = v;
    __syncthreads();
    for (int s = 128; s > 0; s >>= 1) {
        if (threadIdx.x < (unsigned)s) red[threadIdx.x] |= red[threadIdx.x + s];
        __syncthreads();
    }
    if (threadIdx.x == 0) meta[0] = (red[0] == 0) ? 1 : 0;  // 1 => int64
    for (int i = threadIdx.x; i < NBUCK; i += 256) bucket_cursor[i] = 0;
    for (int idx = threadIdx.x; idx < 2 * 4 * 64 * 8; idx += 256) {
        const int j    = idx & 7;
        const int lane = (idx >> 3) & 63;
        const int kk   = (idx >> 9) & 3;
        const int nt   = idx >> 11;
        const int k = kk * 32 + ((lane >> 4) << 3) + j;
        const int n = nt * 16 + (lane & 15);
        W1f[idx] = f2bf(W1[k * H1 + n]);
    }
}

// ---------------- pass A: bucket scatter via block-local LDS counting sort ---
// Paired (int4/int2) coalesced edge loads; edges held in registers. Output
// writes are linear in LDS-sorted order -> wave-coalesced stores into
// per-(block,bucket) exclusive segments at region b*BCAP.

__global__ __launch_bounds__(512) void k_bscatter(const int* __restrict__ ei,
                                                  const int* __restrict__ meta,
                                                  int* __restrict__ bucket_cursor,
                                                  int* __restrict__ ebuf) {
    __shared__ int hist[NBUCK];
    __shared__ int lofs[NBUCK];
    __shared__ int rank[NBUCK];
    __shared__ int gb[NBUCK];
    __shared__ int sc[512];
    __shared__ int pay[EPB];                 // 16 KB
    __shared__ unsigned short pbk[EPB];      // 8 KB
    const int tid = threadIdx.x;
    for (int i = tid; i < NBUCK; i += 512) { hist[i] = 0; rank[i] = 0; }
    __syncthreads();
    const int e0 = blockIdx.x * EPB;
    const int n = min(EPB, N_EDGES - e0);    // always even (N_EDGES % 2 == 0)
    const bool is64 = (meta[0] != 0);
    int rs[EPT], rd[EPT];
    if (is64) {
#pragma unroll
        for (int k = 0; k < EPT / 2; ++k) {
            const int i = 2 * (tid + k * 512);
            if (i < n) {
                const int e = e0 + i;
                const int4 s = *(const int4*)&ei[2 * e];
                const int4 d = *(const int4*)&ei[2 * N_EDGES + 2 * e];
                rs[2 * k] = s.x; rs[2 * k + 1] = s.z;
                rd[2 * k] = d.x; rd[2 * k + 1] = d.z;
                atomicAdd(&hist[d.x >> 8], 1);
                atomicAdd(&hist[d.z >> 8], 1);
            }
        }
    } else {
#pragma unroll
        for (int k = 0; k < EPT / 2; ++k) {
            const int i = 2 * (tid + k * 512);
            if (i < n) {
                const int e = e0 + i;
                const int2 s = *(const int2*)&ei[e];
                const int2 d = *(const int2*)&ei[N_EDGES + e];
                rs[2 * k] = s.x; rs[2 * k + 1] = s.y;
                rd[2 * k] = d.x; rd[2 * k + 1] = d.y;
                atomicAdd(&hist[d.x >> 8], 1);
                atomicAdd(&hist[d.y >> 8], 1);
            }
        }
    }
    __syncthreads();
    const int own = (tid < NBUCK) ? hist[tid] : 0;
    sc[tid] = own;
    __syncthreads();
    for (int off = 1; off < 512; off <<= 1) {
        const int v = (tid >= off) ? sc[tid - off] : 0;
        __syncthreads();
        sc[tid] += v;
        __syncthreads();
    }
    if (tid < NBUCK) {
        lofs[tid] = sc[tid] - own;
        if (own > 0) gb[tid] = tid * BCAP + atomicAdd(&bucket_cursor[tid], own);
    }
    __syncthreads();
#pragma unroll
    for (int k = 0; k < EPT / 2; ++k) {
        const int i = 2 * (tid + k * 512);
        if (i < n) {
#pragma unroll
            for (int j = 0; j < 2; ++j) {
                const int b = rd[2 * k + j] >> 8;
                const int p = lofs[b] + atomicAdd(&rank[b], 1);
                pay[p] = (rs[2 * k + j] << 8) | (rd[2 * k + j] & 255);
                pbk[p] = (unsigned short)b;
            }
        }
    }
    __syncthreads();
    for (int p = tid; p < n; p += 512) {
        const int b = pbk[p];
        ebuf[gb[b] + (p - lofs[b])] = pay[p];
    }
}

// ---------------- pass B: per-bucket scan + degree + LDS sort + fill ---------
// Absorbs the former k_bscan (each block recomputes the 391-wide prefix) and
// stages the bucket sorted in LDS so col_idx stores are linear/coalesced.

__global__ __launch_bounds__(512) void k_bfill2(const int* __restrict__ ebuf,
                                                const int* __restrict__ bucket_cursor,
                                                int* __restrict__ row_ptr,
                                                float* __restrict__ dinv,
                                                int* __restrict__ col_idx) {
    __shared__ int h[512];
    __shared__ int cnt[256];
    __shared__ int sc[256];
    __shared__ int cur[256];
    __shared__ int srt[BCAP];       // 64 KB sorted bucket staging
    __shared__ int s_wb, s_nb;
    const int b = blockIdx.x;
    const int tid = threadIdx.x;
    const int own0 = (tid < NBUCK) ? bucket_cursor[tid] : 0;
    h[tid] = own0;
    if (tid < 256) cnt[tid] = 0;
    __syncthreads();
    for (int off = 1; off < 512; off <<= 1) {
        const int v = (tid >= off) ? h[tid - off] : 0;
        __syncthreads();
        h[tid] += v;
        __syncthreads();
    }
    if (tid == b) { s_wb = h[tid] - own0; s_nb = own0; }
    __syncthreads();
    const int wb = s_wb;
    const int nb = s_nb;
    const int rb = b * BCAP;
    for (int i = tid; i < nb; i += 512)
        atomicAdd(&cnt[ebuf[rb + i] & 255], 1);
    __syncthreads();
    int own = 0;
    if (tid < 256) { own = cnt[tid]; sc[tid] = own; }
    __syncthreads();
    for (int off = 1; off < 256; off <<= 1) {
        const int v = (tid < 256 && tid >= off) ? sc[tid - off] : 0;
        __syncthreads();
        if (tid < 256) sc[tid] += v;
        __syncthreads();
    }
    if (tid < 256) {
        const int excl = sc[tid] - own;
        const int v = (b << 8) + tid;
        if (v <= N_NODES) row_ptr[v] = wb + excl;   // v==N_NODES: bucket 390, tid 160
        if (v < N_NODES) dinv[v] = rsqrtf(1.0f + (float)own);  // +1 self-loop
        cur[tid] = excl;                             // LDS-local cursor
    }
    __syncthreads();
    for (int i = tid; i < nb; i += 512) {
        const int pk = ebuf[rb + i];
        const int slot = atomicAdd(&cur[pk & 255], 1);
        srt[slot] = pk >> 8;
    }
    __syncthreads();
    for (int i = tid; i < nb; i += 512)
        col_idx[wb + i] = srt[i];                    // coalesced linear store
}

// ---------------- layer 1 linear via MFMA: u1q = fp8( dinv * (x @ W1) ) ------

__global__ __launch_bounds__(256) void k_gemm1m(const float* __restrict__ x,
                                                const unsigned short* __restrict__ W1f,
                                                const float* __restrict__ dinv,
                                                unsigned int* __restrict__ u1q) {
    __shared__ float os[4][16][33];
    const int tid = threadIdx.x;
    const int w = tid >> 6;
    const int lane = tid & 63;
    const int row0 = (blockIdx.x * 4 + w) * 16;
    const bool act = (row0 < N_NODES);
    if (act) {
        const int m = lane & 15;
        const int quad = lane >> 4;
        const s16x8* bf = (const s16x8*)W1f;
        f32x4 acc0 = {0.f, 0.f, 0.f, 0.f};
        f32x4 acc1 = {0.f, 0.f, 0.f, 0.f};
#pragma unroll
        for (int kk = 0; kk < 4; ++kk) {
            const float* xp = x + (size_t)(row0 + m) * D_FEAT + kk * 32 + quad * 8;
            const float4 p0 = ((const float4*)xp)[0];
            const float4 p1 = ((const float4*)xp)[1];
            s16x8 a;
            a[0] = (short)f2bf(p0.x); a[1] = (short)f2bf(p0.y);
            a[2] = (short)f2bf(p0.z); a[3] = (short)f2bf(p0.w);
            a[4] = (short)f2bf(p1.x); a[5] = (short)f2bf(p1.y);
            a[6] = (short)f2bf(p1.z); a[7] = (short)f2bf(p1.w);
            acc0 = __builtin_amdgcn_mfma_f32_16x16x32_bf16(a, bf[kk * 64 + lane], acc0, 0, 0, 0);
            acc1 = __builtin_amdgcn_mfma_f32_16x16x32_bf16(a, bf[(4 + kk) * 64 + lane], acc1, 0, 0, 0);
        }
#pragma unroll
        for (int r = 0; r < 4; ++r) {
            os[w][quad * 4 + r][m]      = acc0[r];
            os[w][quad * 4 + r][16 + m] = acc1[r];
        }
    }
    __syncthreads();
    if (act) {
        const int rl = lane >> 2;       // row-in-wave 0..15
        const int seg = lane & 3;       // 8-col segment
        const int row = row0 + rl;
        const float dv = dinv[row];
        const float* p = &os[w][rl][seg * 8];
        unsigned int pk0 = __builtin_amdgcn_cvt_pk_fp8_f32(p[0] * dv, p[1] * dv, 0u, false);
        pk0 = __builtin_amdgcn_cvt_pk_fp8_f32(p[2] * dv, p[3] * dv, pk0, true);
        unsigned int pk1 = __builtin_amdgcn_cvt_pk_fp8_f32(p[4] * dv, p[5] * dv, 0u, false);
        pk1 = __builtin_amdgcn_cvt_pk_fp8_f32(p[6] * dv, p[7] * dv, pk1, true);
        uint2 o; o.x = pk0; o.y = pk1;
        ((uint2*)u1q)[(size_t)row * 4 + seg] = o;
    }
}

// ---------------- fused pull1 + GEMM2 (fp8 gather, 4 lanes/node, MLP x4) -----
// 8-deep gather pipeline; col_idx loaded once per quad (lane-distributed) and
// shared via __shfl within the node's 4-lane group.

#define ACC8(Q) do { \
    a0 += __builtin_amdgcn_cvt_f32_fp8((Q).x, 0); \
    a1 += __builtin_amdgcn_cvt_f32_fp8((Q).x, 1); \
    a2 += __builtin_amdgcn_cvt_f32_fp8((Q).x, 2); \
    a3 += __builtin_amdgcn_cvt_f32_fp8((Q).x, 3); \
    a4 += __builtin_amdgcn_cvt_f32_fp8((Q).y, 0); \
    a5 += __builtin_amdgcn_cvt_f32_fp8((Q).y, 1); \
    a6 += __builtin_amdgcn_cvt_f32_fp8((Q).y, 2); \
    a7 += __builtin_amdgcn_cvt_f32_fp8((Q).y, 3); \
} while (0)

__global__ __launch_bounds__(256) void k_pull1f(const int* __restrict__ row_ptr,
                                                const int* __restrict__ col_idx,
                                                const float* __restrict__ dinv,
                                                const unsigned int* __restrict__ u1q,
                                                const float* __restrict__ b1,
                                                const float* __restrict__ W2,
                                                unsigned int* __restrict__ u2b) {
    __shared__ float Ws[H1 * H2];   // 512
    __shared__ float hs[64][33];    // padded rows
    const int tid = threadIdx.x;
    for (int i = tid; i < H1 * H2; i += 256) Ws[i] = W2[i];
    const int n = tid >> 2;         // node-in-block 0..63
    const int lq = tid & 3;         // lane 0..3 (8 fp8 = 8B each)
    const int lb = (tid & 63) & ~3; // base lane of this node's quad
    const int v = blockIdx.x * 64 + n;
    float dv = 0.0f;
    if (v < N_NODES) {
        const uint2* base = (const uint2*)u1q;
        uint2 q = base[(size_t)v * 4 + lq];  // self-loop term
        float a0 = __builtin_amdgcn_cvt_f32_fp8(q.x, 0);
        float a1 = __builtin_amdgcn_cvt_f32_fp8(q.x, 1);
        float a2 = __builtin_amdgcn_cvt_f32_fp8(q.x, 2);
        float a3 = __builtin_amdgcn_cvt_f32_fp8(q.x, 3);
        float a4 = __builtin_amdgcn_cvt_f32_fp8(q.y, 0);
        float a5 = __builtin_amdgcn_cvt_f32_fp8(q.y, 1);
        float a6 = __builtin_amdgcn_cvt_f32_fp8(q.y, 2);
        float a7 = __builtin_amdgcn_cvt_f32_fp8(q.y, 3);
        const int beg = row_ptr[v];
        const int end = row_ptr[v + 1];
        int i = beg;
        for (; i + 8 <= end; i += 8) {   // 8 independent gather chains in flight
            const int c0 = col_idx[i + lq];
            const int c1 = col_idx[i + 4 + lq];
            const int s0 = __shfl(c0, lb + 0, 64);
            const int s1 = __shfl(c0, lb + 1, 64);
            const int s2 = __shfl(c0, lb + 2, 64);
            const int s3 = __shfl(c0, lb + 3, 64);
            const int s4 = __shfl(c1, lb + 0, 64);
            const int s5 = __shfl(c1, lb + 1, 64);
            const int s6 = __shfl(c1, lb + 2, 64);
            const int s7 = __shfl(c1, lb + 3, 64);
            const uint2 q0 = base[(size_t)s0 * 4 + lq];
            const uint2 q1 = base[(size_t)s1 * 4 + lq];
            const uint2 q2 = base[(size_t)s2 * 4 + lq];
            const uint2 q3 = base[(size_t)s3 * 4 + lq];
            const uint2 q4 = base[(size_t)s4 * 4 + lq];
            const uint2 q5 = base[(size_t)s5 * 4 + lq];
            const uint2 q6 = base[(size_t)s6 * 4 + lq];
            const uint2 q7 = base[(size_t)s7 * 4 + lq];
            ACC8(q0); ACC8(q1); ACC8(q2); ACC8(q3);
            ACC8(q4); ACC8(q5); ACC8(q6); ACC8(q7);
        }
        for (; i + 4 <= end; i += 4) {
            const int c0 = col_idx[i + lq];
            const int s0 = __shfl(c0, lb + 0, 64);
            const int s1 = __shfl(c0, lb + 1, 64);
            const int s2 = __shfl(c0, lb + 2, 64);
            const int s3 = __shfl(c0, lb + 3, 64);
            const uint2 q0 = base[(size_t)s0 * 4 + lq];
            const uint2 q1 = base[(size_t)s1 * 4 + lq];
            const uint2 q2 = base[(size_t)s2 * 4 + lq];
            const uint2 q3 = base[(size_t)s3 * 4 + lq];
            ACC8(q0); ACC8(q1); ACC8(q2); ACC8(q3);
        }
        for (; i < end; ++i) {
            const int s = col_idx[i];
            const uint2 qq = base[(size_t)s * 4 + lq];
            ACC8(qq);
        }
        dv = dinv[v];
        const float4 bb0 = ((const float4*)b1)[lq * 2];
        const float4 bb1 = ((const float4*)b1)[lq * 2 + 1];
        float* hp = &hs[n][lq * 8];
        hp[0] = fmaxf(fmaf(a0, dv, bb0.x), 0.0f);
        hp[1] = fmaxf(fmaf(a1, dv, bb0.y), 0.0f);
        hp[2] = fmaxf(fmaf(a2, dv, bb0.z), 0.0f);
        hp[3] = fmaxf(fmaf(a3, dv, bb0.w), 0.0f);
        hp[4] = fmaxf(fmaf(a4, dv, bb1.x), 0.0f);
        hp[5] = fmaxf(fmaf(a5, dv, bb1.y), 0.0f);
        hp[6] = fmaxf(fmaf(a6, dv, bb1.z), 0.0f);
        hp[7] = fmaxf(fmaf(a7, dv, bb1.w), 0.0f);
    }
    __syncthreads();
    if (v < N_NODES) {
        const int j0 = lq * 4;
        float s0 = 0.f, s1 = 0.f, s2 = 0.f, s3 = 0.f;
#pragma unroll
        for (int k = 0; k < H1; ++k) {
            const float hk = hs[n][k];
            s0 = fmaf(hk, Ws[k * H2 + j0 + 0], s0);
            s1 = fmaf(hk, Ws[k * H2 + j0 + 1], s1);
            s2 = fmaf(hk, Ws[k * H2 + j0 + 2], s2);
            s3 = fmaf(hk, Ws[k * H2 + j0 + 3], s3);
        }
        uint2 o;
        o.x = (unsigned int)f2bf(s0 * dv) | ((unsigned int)f2bf(s1 * dv) << 16);
        o.y = (unsigned int)f2bf(s2 * dv) | ((unsigned int)f2bf(s3 * dv) << 16);
        ((uint2*)u2b)[(size_t)v * 4 + lq] = o;
    }
}

// ---------------- fused pull2 + classifier (4 lanes/node x 8B, MLP x4) -------

#define ACC4(Q) do { \
    a0 += bf2f((unsigned short)(Q).x); \
    a1 += bf2f((unsigned short)((Q).x >> 16)); \
    a2 += bf2f((unsigned short)(Q).y); \
    a3 += bf2f((unsigned short)((Q).y >> 16)); \
} while (0)

__global__ __launch_bounds__(256) void k_pull2f(const int* __restrict__ row_ptr,
                                                const int* __restrict__ col_idx,
                                                const float* __restrict__ dinv,
                                                const unsigned int* __restrict__ u2b,
                                                const float* __restrict__ b2,
                                                const float* __restrict__ Wc,
                                                const float* __restrict__ bc,
                                                float* __restrict__ out) {
    __shared__ float hs[64][17];    // padded rows
    __shared__ float Wcs[H2 * NC];  // 128
    __shared__ float bcs[NC];
    const int tid = threadIdx.x;
    if (tid < H2 * NC) Wcs[tid] = Wc[tid];
    if (tid < NC) bcs[tid] = bc[tid];
    const int n = tid >> 2;         // node-in-block 0..63
    const int lq = tid & 3;         // lane 0..3 (4 bf16 = 8B each)
    const int lb = (tid & 63) & ~3; // base lane of this node's quad
    const int v = blockIdx.x * 64 + n;
    if (v < N_NODES) {
        const uint2* base = (const uint2*)u2b;
        uint2 q = base[(size_t)v * 4 + lq];   // self-loop term
        float a0 = bf2f((unsigned short)q.x), a1 = bf2f((unsigned short)(q.x >> 16));
        float a2 = bf2f((unsigned short)q.y), a3 = bf2f((unsigned short)(q.y >> 16));
        const int beg = row_ptr[v];
        const int end = row_ptr[v + 1];
        int i = beg;
        for (; i + 8 <= end; i += 8) {
            const int c0 = col_idx[i + lq];
            const int c1 = col_idx[i + 4 + lq];
            const int s0 = __shfl(c0, lb + 0, 64);
            const int s1 = __shfl(c0, lb + 1, 64);
            const int s2 = __shfl(c0, lb + 2, 64);
            const int s3 = __shfl(c0, lb + 3, 64);
            const int s4 = __shfl(c1, lb + 0, 64);
            const int s5 = __shfl(c1, lb + 1, 64);
            const int s6 = __shfl(c1, lb + 2, 64);
            const int s7 = __shfl(c1, lb + 3, 64);
            const uint2 q0 = base[(size_t)s0 * 4 + lq];
            const uint2 q1 = base[(size_t)s1 * 4 + lq];
            const uint2 q2 = base[(size_t)s2 * 4 + lq];
            const uint2 q3 = base[(size_t)s3 * 4 + lq];
            const uint2 q4 = base[(size_t)s4 * 4 + lq];
            const uint2 q5 = base[(size_t)s5 * 4 + lq];
            const uint2 q6 = base[(size_t)s6 * 4 + lq];
            const uint2 q7 = base[(size_t)s7 * 4 + lq];
            ACC4(q0); ACC4(q1); ACC4(q2); ACC4(q3);
            ACC4(q4); ACC4(q5); ACC4(q6); ACC4(q7);
        }
        for (; i + 4 <= end; i += 4) {
            const int c0 = col_idx[i + lq];
            const int s0 = __shfl(c0, lb + 0, 64);
            const int s1 = __shfl(c0, lb + 1, 64);
            const int s2 = __shfl(c0, lb + 2, 64);
            const int s3 = __shfl(c0, lb + 3, 64);
            const uint2 q0 = base[(size_t)s0 * 4 + lq];
            const uint2 q1 = base[(size_t)s1 * 4 + lq];
            const uint2 q2 = base[(size_t)s2 * 4 + lq];
            const uint2 q3 = base[(size_t)s3 * 4 + lq];
            ACC4(q0); ACC4(q1); ACC4(q2); ACC4(q3);
        }
        for (; i < end; ++i) {
            const int s = col_idx[i];
            const uint2 qq = base[(size_t)s * 4 + lq];
            ACC4(qq);
        }
        const float dv = dinv[v];
        const float4 bb = ((const float4*)b2)[lq];
        float* hp = &hs[n][lq * 4];
        hp[0] = fmaxf(fmaf(a0, dv, bb.x), 0.0f);
        hp[1] = fmaxf(fmaf(a1, dv, bb.y), 0.0f);
        hp[2] = fmaxf(fmaf(a2, dv, bb.z), 0.0f);
        hp[3] = fmaxf(fmaf(a3, dv, bb.w), 0.0f);
    }
    __syncthreads();
    if (tid < 64) {
        const int vv = blockIdx.x * 64 + tid;
        if (vv < N_NODES) {
            float lg[NC];
#pragma unroll
            for (int j = 0; j < NC; ++j) lg[j] = bcs[j];
#pragma unroll
            for (int k = 0; k < H2; ++k) {
                const float hk = hs[tid][k];
#pragma unroll
                for (int j = 0; j < NC; ++j)
                    lg[j] = fmaf(hk, Wcs[k * NC + j], lg[j]);
            }
            float m = lg[0];
#pragma unroll
            for (int j = 1; j < NC; ++j) m = fmaxf(m, lg[j]);
            float s = 0.0f;
#pragma unroll
            for (int j = 0; j < NC; ++j) s += expf(lg[j] - m);
            const float lse = logf(s) + m;
            float4 o0, o1;
            o0.x = lg[0] - lse; o0.y = lg[1] - lse;
            o0.z = lg[2] - lse; o0.w = lg[3] - lse;
            o1.x = lg[4] - lse; o1.y = lg[5] - lse;
            o1.z = lg[6] - lse; o1.w = lg[7] - lse;
            float4* op = (float4*)(out + (size_t)vv * NC);
            op[0] = o0; op[1] = o1;
        }
    }
}

// ---------------- host launch ----------------

extern "C" void kernel_launch(void* const* d_in, const int* in_sizes, int n_in,
                              void* d_out, int out_size, void* d_ws, size_t ws_size,
                              hipStream_t stream) {
    const float* x   = (const float*)d_in[0];
    const int*   ei  = (const int*)d_in[1];
    const float* W1  = (const float*)d_in[2];
    const float* b1  = (const float*)d_in[3];
    const float* W2  = (const float*)d_in[4];
    const float* b2  = (const float*)d_in[5];
    const float* Wc  = (const float*)d_in[6];
    const float* bc  = (const float*)d_in[7];
    float* out = (float*)d_out;

    // workspace layout (int units). ~43 MB total.
    int*   meta          = (int*)d_ws;                      // 16
    int*   bucket_cursor = meta + 16;                       // 512
    int*   bucket_base   = bucket_cursor + 512;             // 512 (reserved, unused)
    int*   row_ptr       = bucket_base + 512;               // 100016 (100001 used)
    float* dinv          = (float*)(row_ptr + 100016);      // 100000
    unsigned short* W1f  = (unsigned short*)(dinv + 100000);// 4096 bf16 (2048 ints)
    int*   col_idx       = (int*)W1f + 2048;                // 3200000
    int*   ebuf          = col_idx + 3200000;               // NBUCK*BCAP = 6406144
    // u1q (fp8, 3.2 MB) aliases ebuf (dead after k_bfill2); u2b beyond ebuf.
    unsigned int* u1q    = (unsigned int*)ebuf;             // 800000 dwords
    unsigned int* u2b    = (unsigned int*)(ebuf + NBUCK * BCAP); // 800000 dwords

    k_detect  <<<1, 256, 0, stream>>>(ei, W1, meta, bucket_cursor, W1f);
    k_bscatter<<<(N_EDGES + EPB - 1) / EPB, 512, 0, stream>>>(ei, meta, bucket_cursor, ebuf);
    k_bfill2  <<<NBUCK, 512, 0, stream>>>(ebuf, bucket_cursor, row_ptr, dinv, col_idx);

    k_gemm1m<<<(N_NODES + 63) / 64, 256, 0, stream>>>(x, W1f, dinv, u1q);
    k_pull1f<<<(N_NODES + 63) / 64, 256, 0, stream>>>(row_ptr, col_idx, dinv, u1q, b1, W2, u2b);
    k_pull2f<<<(N_NODES + 63) / 64, 256, 0, stream>>>(row_ptr, col_idx, dinv, u2b, b2, Wc, bc, out);
}

// Round 3
// 199.998 us; speedup vs baseline: 1.1159x; 1.0492x over previous
//
#include <hip/hip_runtime.h>
#include <math.h>

#define N_NODES 100000
#define N_EDGES 3200000
#define D_FEAT 128
#define H1 32
#define H2 16
#define NC 8

#define NBUCK 391          // buckets of 256 dst nodes: ceil(100000/256)
#define BCAP 16384         // fixed ebuf slots per bucket
#define EPB 4096           // edges per k_bscatter block (4 blocks/CU)
#define EPT 8              // edges per thread (EPB / 512)

#define P_NODES 32         // nodes per pull block (100000 % 32 == 0)
#define P_CAP 3072         // staged col_idx slots (avg range ~1024)

typedef short s16x8 __attribute__((ext_vector_type(8)));
typedef float f32x4 __attribute__((ext_vector_type(4)));

// bf16 helpers (round-to-nearest-even pack, shift-expand)
__device__ inline unsigned short f2bf(float f) {
    unsigned int u = __float_as_uint(f);
    u += 0x7FFF + ((u >> 16) & 1);
    return (unsigned short)(u >> 16);
}
__device__ inline float bf2f(unsigned short h) {
    return __uint_as_float((unsigned int)h << 16);
}

// 64-lane inclusive scan, no barriers
__device__ inline int wave_scan_incl(int v, int lane) {
#pragma unroll
    for (int off = 1; off < 64; off <<= 1) {
        const int t = __shfl_up(v, off, 64);
        if (lane >= off) v += t;
    }
    return v;
}

// ---------------- detect edge dtype + zero cursors + W1 B-fragment prep ------

__global__ void k_detect(const int* __restrict__ ei, const float* __restrict__ W1,
                         int* __restrict__ meta, int* __restrict__ bucket_cursor,
                         unsigned short* __restrict__ W1f) {
    __shared__ int red[256];
    int v = 0;
    for (int i = threadIdx.x; i < 1024; i += 256) v |= ei[2 * i + 1];
    red[threadIdx.x] = v;
    __syncthreads();
    for (int s = 128; s > 0; s >>= 1) {
        if (threadIdx.x < (unsigned)s) red[threadIdx.x] |= red[threadIdx.x + s];
        __syncthreads();
    }
    if (threadIdx.x == 0) meta[0] = (red[0] == 0) ? 1 : 0;  // 1 => int64
    for (int i = threadIdx.x; i < NBUCK; i += 256) bucket_cursor[i] = 0;
    for (int idx = threadIdx.x; idx < 2 * 4 * 64 * 8; idx += 256) {
        const int j    = idx & 7;
        const int lane = (idx >> 3) & 63;
        const int kk   = (idx >> 9) & 3;
        const int nt   = idx >> 11;
        const int k = kk * 32 + ((lane >> 4) << 3) + j;
        const int n = nt * 16 + (lane & 15);
        W1f[idx] = f2bf(W1[k * H1 + n]);
    }
}

// ---------------- pass A: bucket scatter via block-local LDS counting sort ---

__global__ __launch_bounds__(512) void k_bscatter(const int* __restrict__ ei,
                                                  const int* __restrict__ meta,
                                                  int* __restrict__ bucket_cursor,
                                                  int* __restrict__ ebuf) {
    __shared__ int hist[NBUCK];
    __shared__ int lofs[NBUCK];
    __shared__ int rank[NBUCK];
    __shared__ int gb[NBUCK];
    __shared__ int wsum[8];
    __shared__ int pay[EPB];                 // 16 KB
    __shared__ unsigned short pbk[EPB];      // 8 KB
    const int tid = threadIdx.x;
    const int lane = tid & 63;
    const int wid = tid >> 6;
    for (int i = tid; i < NBUCK; i += 512) { hist[i] = 0; rank[i] = 0; }
    __syncthreads();
    const int e0 = blockIdx.x * EPB;
    const int n = min(EPB, N_EDGES - e0);    // always even (N_EDGES % 2 == 0)
    const bool is64 = (meta[0] != 0);
    int rs[EPT], rd[EPT];
    if (is64) {
#pragma unroll
        for (int k = 0; k < EPT / 2; ++k) {
            const int i = 2 * (tid + k * 512);
            if (i < n) {
                const int e = e0 + i;
                const int4 s = *(const int4*)&ei[2 * e];
                const int4 d = *(const int4*)&ei[2 * N_EDGES + 2 * e];
                rs[2 * k] = s.x; rs[2 * k + 1] = s.z;
                rd[2 * k] = d.x; rd[2 * k + 1] = d.z;
                atomicAdd(&hist[d.x >> 8], 1);
                atomicAdd(&hist[d.z >> 8], 1);
            }
        }
    } else {
#pragma unroll
        for (int k = 0; k < EPT / 2; ++k) {
            const int i = 2 * (tid + k * 512);
            if (i < n) {
                const int e = e0 + i;
                const int2 s = *(const int2*)&ei[e];
                const int2 d = *(const int2*)&ei[N_EDGES + e];
                rs[2 * k] = s.x; rs[2 * k + 1] = s.y;
                rd[2 * k] = d.x; rd[2 * k + 1] = d.y;
                atomicAdd(&hist[d.x >> 8], 1);
                atomicAdd(&hist[d.y >> 8], 1);
            }
        }
    }
    __syncthreads();
    const int own = (tid < NBUCK) ? hist[tid] : 0;
    int incl = wave_scan_incl(own, lane);
    if (lane == 63) wsum[wid] = incl;
    __syncthreads();
    if (tid == 0) {
        int r = 0;
#pragma unroll
        for (int w = 0; w < 8; ++w) { const int t = wsum[w]; wsum[w] = r; r += t; }
    }
    __syncthreads();
    incl += wsum[wid];
    if (tid < NBUCK) {
        lofs[tid] = incl - own;
        if (own > 0) gb[tid] = tid * BCAP + atomicAdd(&bucket_cursor[tid], own);
    }
    __syncthreads();
#pragma unroll
    for (int k = 0; k < EPT / 2; ++k) {
        const int i = 2 * (tid + k * 512);
        if (i < n) {
#pragma unroll
            for (int j = 0; j < 2; ++j) {
                const int b = rd[2 * k + j] >> 8;
                const int p = lofs[b] + atomicAdd(&rank[b], 1);
                pay[p] = (rs[2 * k + j] << 8) | (rd[2 * k + j] & 255);
                pbk[p] = (unsigned short)b;
            }
        }
    }
    __syncthreads();
    for (int p = tid; p < n; p += 512) {
        const int b = pbk[p];
        ebuf[gb[b] + (p - lofs[b])] = pay[p];
    }
}

// ---------------- pass B: per-bucket scan + degree + LDS sort + fill ---------

__global__ __launch_bounds__(512) void k_bfill2(const int* __restrict__ ebuf,
                                                const int* __restrict__ bucket_cursor,
                                                int* __restrict__ row_ptr,
                                                float* __restrict__ dinv,
                                                int* __restrict__ col_idx) {
    __shared__ int cnt[256];
    __shared__ int cur[256];
    __shared__ int wsum[8];
    __shared__ int srt[BCAP];       // 64 KB sorted bucket staging
    __shared__ int s_wb, s_nb;
    const int b = blockIdx.x;
    const int tid = threadIdx.x;
    const int lane = tid & 63;
    const int wid = tid >> 6;
    const int own0 = (tid < NBUCK) ? bucket_cursor[tid] : 0;
    if (tid < 256) cnt[tid] = 0;
    int incl0 = wave_scan_incl(own0, lane);
    if (lane == 63) wsum[wid] = incl0;
    __syncthreads();
    if (tid == 0) {
        int r = 0;
#pragma unroll
        for (int w = 0; w < 8; ++w) { const int t = wsum[w]; wsum[w] = r; r += t; }
    }
    __syncthreads();
    incl0 += wsum[wid];
    if (tid == b) { s_wb = incl0 - own0; s_nb = own0; }
    __syncthreads();
    const int wb = s_wb;
    const int nb = s_nb;
    const int rb = b * BCAP;
    for (int i = tid; i < nb; i += 512)
        atomicAdd(&cnt[ebuf[rb + i] & 255], 1);
    __syncthreads();
    const int own = (tid < 256) ? cnt[tid] : 0;
    int incl = wave_scan_incl(own, lane);
    if (lane == 63) wsum[wid] = incl;
    __syncthreads();
    if (tid == 0) {
        int r = 0;
#pragma unroll
        for (int w = 0; w < 8; ++w) { const int t = wsum[w]; wsum[w] = r; r += t; }
    }
    __syncthreads();
    incl += wsum[wid];
    if (tid < 256) {
        const int excl = incl - own;
        const int v = (b << 8) + tid;
        if (v <= N_NODES) row_ptr[v] = wb + excl;   // v==N_NODES: bucket 390, tid 160
        if (v < N_NODES) dinv[v] = rsqrtf(1.0f + (float)own);  // +1 self-loop
        cur[tid] = excl;                             // LDS-local cursor
    }
    __syncthreads();
    for (int i = tid; i < nb; i += 512) {
        const int pk = ebuf[rb + i];
        const int slot = atomicAdd(&cur[pk & 255], 1);
        srt[slot] = pk >> 8;
    }
    __syncthreads();
    for (int i = tid; i < nb; i += 512)
        col_idx[wb + i] = srt[i];                    // coalesced linear store
}

// ---------------- layer 1 linear via MFMA: u1q = fp8( dinv * (x @ W1) ) ------

__global__ __launch_bounds__(256) void k_gemm1m(const float* __restrict__ x,
                                                const unsigned short* __restrict__ W1f,
                                                const float* __restrict__ dinv,
                                                unsigned int* __restrict__ u1q) {
    __shared__ float os[4][16][33];
    const int tid = threadIdx.x;
    const int w = tid >> 6;
    const int lane = tid & 63;
    const int row0 = (blockIdx.x * 4 + w) * 16;
    const bool act = (row0 < N_NODES);
    if (act) {
        const int m = lane & 15;
        const int quad = lane >> 4;
        const s16x8* bf = (const s16x8*)W1f;
        f32x4 acc0 = {0.f, 0.f, 0.f, 0.f};
        f32x4 acc1 = {0.f, 0.f, 0.f, 0.f};
#pragma unroll
        for (int kk = 0; kk < 4; ++kk) {
            const float* xp = x + (size_t)(row0 + m) * D_FEAT + kk * 32 + quad * 8;
            const float4 p0 = ((const float4*)xp)[0];
            const float4 p1 = ((const float4*)xp)[1];
            s16x8 a;
            a[0] = (short)f2bf(p0.x); a[1] = (short)f2bf(p0.y);
            a[2] = (short)f2bf(p0.z); a[3] = (short)f2bf(p0.w);
            a[4] = (short)f2bf(p1.x); a[5] = (short)f2bf(p1.y);
            a[6] = (short)f2bf(p1.z); a[7] = (short)f2bf(p1.w);
            acc0 = __builtin_amdgcn_mfma_f32_16x16x32_bf16(a, bf[kk * 64 + lane], acc0, 0, 0, 0);
            acc1 = __builtin_amdgcn_mfma_f32_16x16x32_bf16(a, bf[(4 + kk) * 64 + lane], acc1, 0, 0, 0);
        }
#pragma unroll
        for (int r = 0; r < 4; ++r) {
            os[w][quad * 4 + r][m]      = acc0[r];
            os[w][quad * 4 + r][16 + m] = acc1[r];
        }
    }
    __syncthreads();
    if (act) {
        const int rl = lane >> 2;       // row-in-wave 0..15
        const int seg = lane & 3;       // 8-col segment
        const int row = row0 + rl;
        const float dv = dinv[row];
        const float* p = &os[w][rl][seg * 8];
        unsigned int pk0 = __builtin_amdgcn_cvt_pk_fp8_f32(p[0] * dv, p[1] * dv, 0u, false);
        pk0 = __builtin_amdgcn_cvt_pk_fp8_f32(p[2] * dv, p[3] * dv, pk0, true);
        unsigned int pk1 = __builtin_amdgcn_cvt_pk_fp8_f32(p[4] * dv, p[5] * dv, 0u, false);
        pk1 = __builtin_amdgcn_cvt_pk_fp8_f32(p[6] * dv, p[7] * dv, pk1, true);
        uint2 o; o.x = pk0; o.y = pk1;
        ((uint2*)u1q)[(size_t)row * 4 + seg] = o;
    }
}

// ---------------- fused pull1 + GEMM2 ----------------------------------------
// 32 nodes/block, 8 lanes/node (even/odd edge streams x 4 feature lanes).
// Block's col_idx slice staged in LDS (coalesced); gather chain: LDS idx ->
// L2 gather, 8 deep per stream. Halves combine with one shfl_xor(4).

#define ACC8(Q) do { \
    a0 += __builtin_amdgcn_cvt_f32_fp8((Q).x, 0); \
    a1 += __builtin_amdgcn_cvt_f32_fp8((Q).x, 1); \
    a2 += __builtin_amdgcn_cvt_f32_fp8((Q).x, 2); \
    a3 += __builtin_amdgcn_cvt_f32_fp8((Q).x, 3); \
    a4 += __builtin_amdgcn_cvt_f32_fp8((Q).y, 0); \
    a5 += __builtin_amdgcn_cvt_f32_fp8((Q).y, 1); \
    a6 += __builtin_amdgcn_cvt_f32_fp8((Q).y, 2); \
    a7 += __builtin_amdgcn_cvt_f32_fp8((Q).y, 3); \
} while (0)

__global__ __launch_bounds__(256) void k_pull1f(const int* __restrict__ row_ptr,
                                                const int* __restrict__ col_idx,
                                                const float* __restrict__ dinv,
                                                const unsigned int* __restrict__ u1q,
                                                const float* __restrict__ b1,
                                                const float* __restrict__ W2,
                                                unsigned int* __restrict__ u2b) {
    __shared__ float Ws[H1 * H2];       // 2 KB
    __shared__ float hs[P_NODES][33];   // h + dv in col 32
    __shared__ int lidx[P_CAP];         // 12 KB staged indices
    const int tid = threadIdx.x;
    for (int i = tid; i < H1 * H2; i += 256) Ws[i] = W2[i];
    const int v0 = blockIdx.x * P_NODES;
    const int base_off = row_ptr[v0];
    const int range = row_ptr[v0 + P_NODES] - base_off;
    const bool ovf = (range > P_CAP);
    const int stg = ovf ? 0 : range;
    for (int j = tid; j < stg; j += 256) lidx[j] = col_idx[base_off + j];
    __syncthreads();
    const int n = tid >> 3;         // node-in-block 0..31
    const int half = (tid >> 2) & 1;
    const int lq = tid & 3;         // feature lane (8 fp8 = 8B each)
    const int v = v0 + n;           // always < N_NODES (100000 % 32 == 0)
    const uint2* base = (const uint2*)u1q;
    float a0 = 0.f, a1 = 0.f, a2 = 0.f, a3 = 0.f;
    float a4 = 0.f, a5 = 0.f, a6 = 0.f, a7 = 0.f;
    if (half == 0) {                // self-loop term counted once
        const uint2 q = base[(size_t)v * 4 + lq];
        a0 = __builtin_amdgcn_cvt_f32_fp8(q.x, 0);
        a1 = __builtin_amdgcn_cvt_f32_fp8(q.x, 1);
        a2 = __builtin_amdgcn_cvt_f32_fp8(q.x, 2);
        a3 = __builtin_amdgcn_cvt_f32_fp8(q.x, 3);
        a4 = __builtin_amdgcn_cvt_f32_fp8(q.y, 0);
        a5 = __builtin_amdgcn_cvt_f32_fp8(q.y, 1);
        a6 = __builtin_amdgcn_cvt_f32_fp8(q.y, 2);
        a7 = __builtin_amdgcn_cvt_f32_fp8(q.y, 3);
    }
    const int beg = row_ptr[v] - base_off;
    const int end = row_ptr[v + 1] - base_off;
    int i = beg + half;
    if (!ovf) {
        for (; i + 14 < end; i += 16) {     // 8 gathers in flight per stream
            const int s0 = lidx[i];
            const int s1 = lidx[i + 2];
            const int s2 = lidx[i + 4];
            const int s3 = lidx[i + 6];
            const int s4 = lidx[i + 8];
            const int s5 = lidx[i + 10];
            const int s6 = lidx[i + 12];
            const int s7 = lidx[i + 14];
            const uint2 q0 = base[(size_t)s0 * 4 + lq];
            const uint2 q1 = base[(size_t)s1 * 4 + lq];
            const uint2 q2 = base[(size_t)s2 * 4 + lq];
            const uint2 q3 = base[(size_t)s3 * 4 + lq];
            const uint2 q4 = base[(size_t)s4 * 4 + lq];
            const uint2 q5 = base[(size_t)s5 * 4 + lq];
            const uint2 q6 = base[(size_t)s6 * 4 + lq];
            const uint2 q7 = base[(size_t)s7 * 4 + lq];
            ACC8(q0); ACC8(q1); ACC8(q2); ACC8(q3);
            ACC8(q4); ACC8(q5); ACC8(q6); ACC8(q7);
        }
        for (; i + 6 < end; i += 8) {
            const int s0 = lidx[i];
            const int s1 = lidx[i + 2];
            const int s2 = lidx[i + 4];
            const int s3 = lidx[i + 6];
            const uint2 q0 = base[(size_t)s0 * 4 + lq];
            const uint2 q1 = base[(size_t)s1 * 4 + lq];
            const uint2 q2 = base[(size_t)s2 * 4 + lq];
            const uint2 q3 = base[(size_t)s3 * 4 + lq];
            ACC8(q0); ACC8(q1); ACC8(q2); ACC8(q3);
        }
        for (; i < end; i += 2) {
            const uint2 qq = base[(size_t)lidx[i] * 4 + lq];
            ACC8(qq);
        }
    } else {
        const int* gp = col_idx + base_off;
        for (; i + 14 < end; i += 16) {
            const int s0 = gp[i];
            const int s1 = gp[i + 2];
            const int s2 = gp[i + 4];
            const int s3 = gp[i + 6];
            const int s4 = gp[i + 8];
            const int s5 = gp[i + 10];
            const int s6 = gp[i + 12];
            const int s7 = gp[i + 14];
            const uint2 q0 = base[(size_t)s0 * 4 + lq];
            const uint2 q1 = base[(size_t)s1 * 4 + lq];
            const uint2 q2 = base[(size_t)s2 * 4 + lq];
            const uint2 q3 = base[(size_t)s3 * 4 + lq];
            const uint2 q4 = base[(size_t)s4 * 4 + lq];
            const uint2 q5 = base[(size_t)s5 * 4 + lq];
            const uint2 q6 = base[(size_t)s6 * 4 + lq];
            const uint2 q7 = base[(size_t)s7 * 4 + lq];
            ACC8(q0); ACC8(q1); ACC8(q2); ACC8(q3);
            ACC8(q4); ACC8(q5); ACC8(q6); ACC8(q7);
        }
        for (; i < end; i += 2) {
            const uint2 qq = base[(size_t)gp[i] * 4 + lq];
            ACC8(qq);
        }
    }
    // combine even/odd streams
    a0 += __shfl_xor(a0, 4, 64); a1 += __shfl_xor(a1, 4, 64);
    a2 += __shfl_xor(a2, 4, 64); a3 += __shfl_xor(a3, 4, 64);
    a4 += __shfl_xor(a4, 4, 64); a5 += __shfl_xor(a5, 4, 64);
    a6 += __shfl_xor(a6, 4, 64); a7 += __shfl_xor(a7, 4, 64);
    if (half == 0) {
        const float dv = dinv[v];
        const float4 bb0 = ((const float4*)b1)[lq * 2];
        const float4 bb1 = ((const float4*)b1)[lq * 2 + 1];
        float* hp = &hs[n][lq * 8];
        hp[0] = fmaxf(fmaf(a0, dv, bb0.x), 0.0f);
        hp[1] = fmaxf(fmaf(a1, dv, bb0.y), 0.0f);
        hp[2] = fmaxf(fmaf(a2, dv, bb0.z), 0.0f);
        hp[3] = fmaxf(fmaf(a3, dv, bb0.w), 0.0f);
        hp[4] = fmaxf(fmaf(a4, dv, bb1.x), 0.0f);
        hp[5] = fmaxf(fmaf(a5, dv, bb1.y), 0.0f);
        hp[6] = fmaxf(fmaf(a6, dv, bb1.z), 0.0f);
        hp[7] = fmaxf(fmaf(a7, dv, bb1.w), 0.0f);
        if (lq == 0) hs[n][32] = dv;
    }
    __syncthreads();
    if (tid < 4 * P_NODES) {
        const int nn = tid >> 2;
        const int jq = tid & 3;
        const int vv = v0 + nn;
        const int j0 = jq * 4;
        const float dv = hs[nn][32];
        float s0 = 0.f, s1 = 0.f, s2 = 0.f, s3 = 0.f;
#pragma unroll
        for (int k = 0; k < H1; ++k) {
            const float hk = hs[nn][k];
            s0 = fmaf(hk, Ws[k * H2 + j0 + 0], s0);
            s1 = fmaf(hk, Ws[k * H2 + j0 + 1], s1);
            s2 = fmaf(hk, Ws[k * H2 + j0 + 2], s2);
            s3 = fmaf(hk, Ws[k * H2 + j0 + 3], s3);
        }
        uint2 o;
        o.x = (unsigned int)f2bf(s0 * dv) | ((unsigned int)f2bf(s1 * dv) << 16);
        o.y = (unsigned int)f2bf(s2 * dv) | ((unsigned int)f2bf(s3 * dv) << 16);
        ((uint2*)u2b)[(size_t)vv * 4 + jq] = o;
    }
}

// ---------------- fused pull2 + classifier -----------------------------------

#define ACC4(Q) do { \
    a0 += bf2f((unsigned short)(Q).x); \
    a1 += bf2f((unsigned short)((Q).x >> 16)); \
    a2 += bf2f((unsigned short)(Q).y); \
    a3 += bf2f((unsigned short)((Q).y >> 16)); \
} while (0)

__global__ __launch_bounds__(256) void k_pull2f(const int* __restrict__ row_ptr,
                                                const int* __restrict__ col_idx,
                                                const float* __restrict__ dinv,
                                                const unsigned int* __restrict__ u2b,
                                                const float* __restrict__ b2,
                                                const float* __restrict__ Wc,
                                                const float* __restrict__ bc,
                                                float* __restrict__ out) {
    __shared__ float hs[P_NODES][17];
    __shared__ float Wcs[H2 * NC];  // 128
    __shared__ float bcs[NC];
    __shared__ int lidx[P_CAP];     // 12 KB
    const int tid = threadIdx.x;
    if (tid < H2 * NC) Wcs[tid] = Wc[tid];
    if (tid < NC) bcs[tid] = bc[tid];
    const int v0 = blockIdx.x * P_NODES;
    const int base_off = row_ptr[v0];
    const int range = row_ptr[v0 + P_NODES] - base_off;
    const bool ovf = (range > P_CAP);
    const int stg = ovf ? 0 : range;
    for (int j = tid; j < stg; j += 256) lidx[j] = col_idx[base_off + j];
    __syncthreads();
    const int n = tid >> 3;
    const int half = (tid >> 2) & 1;
    const int lq = tid & 3;
    const int v = v0 + n;
    const uint2* base = (const uint2*)u2b;
    float a0 = 0.f, a1 = 0.f, a2 = 0.f, a3 = 0.f;
    if (half == 0) {
        const uint2 q = base[(size_t)v * 4 + lq];
        a0 = bf2f((unsigned short)q.x); a1 = bf2f((unsigned short)(q.x >> 16));
        a2 = bf2f((unsigned short)q.y); a3 = bf2f((unsigned short)(q.y >> 16));
    }
    const int beg = row_ptr[v] - base_off;
    const int end = row_ptr[v + 1] - base_off;
    int i = beg + half;
    if (!ovf) {
        for (; i + 14 < end; i += 16) {
            const int s0 = lidx[i];
            const int s1 = lidx[i + 2];
            const int s2 = lidx[i + 4];
            const int s3 = lidx[i + 6];
            const int s4 = lidx[i + 8];
            const int s5 = lidx[i + 10];
            const int s6 = lidx[i + 12];
            const int s7 = lidx[i + 14];
            const uint2 q0 = base[(size_t)s0 * 4 + lq];
            const uint2 q1 = base[(size_t)s1 * 4 + lq];
            const uint2 q2 = base[(size_t)s2 * 4 + lq];
            const uint2 q3 = base[(size_t)s3 * 4 + lq];
            const uint2 q4 = base[(size_t)s4 * 4 + lq];
            const uint2 q5 = base[(size_t)s5 * 4 + lq];
            const uint2 q6 = base[(size_t)s6 * 4 + lq];
            const uint2 q7 = base[(size_t)s7 * 4 + lq];
            ACC4(q0); ACC4(q1); ACC4(q2); ACC4(q3);
            ACC4(q4); ACC4(q5); ACC4(q6); ACC4(q7);
        }
        for (; i + 6 < end; i += 8) {
            const int s0 = lidx[i];
            const int s1 = lidx[i + 2];
            const int s2 = lidx[i + 4];
            const int s3 = lidx[i + 6];
            const uint2 q0 = base[(size_t)s0 * 4 + lq];
            const uint2 q1 = base[(size_t)s1 * 4 + lq];
            const uint2 q2 = base[(size_t)s2 * 4 + lq];
            const uint2 q3 = base[(size_t)s3 * 4 + lq];
            ACC4(q0); ACC4(q1); ACC4(q2); ACC4(q3);
        }
        for (; i < end; i += 2) {
            const uint2 qq = base[(size_t)lidx[i] * 4 + lq];
            ACC4(qq);
        }
    } else {
        const int* gp = col_idx + base_off;
        for (; i + 14 < end; i += 16) {
            const int s0 = gp[i];
            const int s1 = gp[i + 2];
            const int s2 = gp[i + 4];
            const int s3 = gp[i + 6];
            const int s4 = gp[i + 8];
            const int s5 = gp[i + 10];
            const int s6 = gp[i + 12];
            const int s7 = gp[i + 14];
            const uint2 q0 = base[(size_t)s0 * 4 + lq];
            const uint2 q1 = base[(size_t)s1 * 4 + lq];
            const uint2 q2 = base[(size_t)s2 * 4 + lq];
            const uint2 q3 = base[(size_t)s3 * 4 + lq];
            const uint2 q4 = base[(size_t)s4 * 4 + lq];
            const uint2 q5 = base[(size_t)s5 * 4 + lq];
            const uint2 q6 = base[(size_t)s6 * 4 + lq];
            const uint2 q7 = base[(size_t)s7 * 4 + lq];
            ACC4(q0); ACC4(q1); ACC4(q2); ACC4(q3);
            ACC4(q4); ACC4(q5); ACC4(q6); ACC4(q7);
        }
        for (; i < end; i += 2) {
            const uint2 qq = base[(size_t)gp[i] * 4 + lq];
            ACC4(qq);
        }
    }
    a0 += __shfl_xor(a0, 4, 64); a1 += __shfl_xor(a1, 4, 64);
    a2 += __shfl_xor(a2, 4, 64); a3 += __shfl_xor(a3, 4, 64);
    if (half == 0) {
        const float dv = dinv[v];
        const float4 bb = ((const float4*)b2)[lq];
        float* hp = &hs[n][lq * 4];
        hp[0] = fmaxf(fmaf(a0, dv, bb.x), 0.0f);
        hp[1] = fmaxf(fmaf(a1, dv, bb.y), 0.0f);
        hp[2] = fmaxf(fmaf(a2, dv, bb.z), 0.0f);
        hp[3] = fmaxf(fmaf(a3, dv, bb.w), 0.0f);
    }
    __syncthreads();
    if (tid < P_NODES) {
        const int vv = v0 + tid;
        float lg[NC];
#pragma unroll
        for (int j = 0; j < NC; ++j) lg[j] = bcs[j];
#pragma unroll
        for (int k = 0; k < H2; ++k) {
            const float hk = hs[tid][k];
#pragma unroll
            for (int j = 0; j < NC; ++j)
                lg[j] = fmaf(hk, Wcs[k * NC + j], lg[j]);
        }
        float m = lg[0];
#pragma unroll
        for (int j = 1; j < NC; ++j) m = fmaxf(m, lg[j]);
        float s = 0.0f;
#pragma unroll
        for (int j = 0; j < NC; ++j) s += expf(lg[j] - m);
        const float lse = logf(s) + m;
        float4 o0, o1;
        o0.x = lg[0] - lse; o0.y = lg[1] - lse;
        o0.z = lg[2] - lse; o0.w = lg[3] - lse;
        o1.x = lg[4] - lse; o1.y = lg[5] - lse;
        o1.z = lg[6] - lse; o1.w = lg[7] - lse;
        float4* op = (float4*)(out + (size_t)vv * NC);
        op[0] = o0; op[1] = o1;
    }
}

// ---------------- host launch ----------------

extern "C" void kernel_launch(void* const* d_in, const int* in_sizes, int n_in,
                              void* d_out, int out_size, void* d_ws, size_t ws_size,
                              hipStream_t stream) {
    const float* x   = (const float*)d_in[0];
    const int*   ei  = (const int*)d_in[1];
    const float* W1  = (const float*)d_in[2];
    const float* b1  = (const float*)d_in[3];
    const float* W2  = (const float*)d_in[4];
    const float* b2  = (const float*)d_in[5];
    const float* Wc  = (const float*)d_in[6];
    const float* bc  = (const float*)d_in[7];
    float* out = (float*)d_out;

    // workspace layout (int units). ~43 MB total.
    int*   meta          = (int*)d_ws;                      // 16
    int*   bucket_cursor = meta + 16;                       // 512
    int*   bucket_base   = bucket_cursor + 512;             // 512 (reserved)
    int*   row_ptr       = bucket_base + 512;               // 100016 (100001 used)
    float* dinv          = (float*)(row_ptr + 100016);      // 100000
    unsigned short* W1f  = (unsigned short*)(dinv + 100000);// 4096 bf16 (2048 ints)
    int*   col_idx       = (int*)W1f + 2048;                // 3200000
    int*   ebuf          = col_idx + 3200000;               // NBUCK*BCAP = 6406144
    // u1q (fp8, 3.2 MB) aliases ebuf (dead after k_bfill2); u2b beyond ebuf.
    unsigned int* u1q    = (unsigned int*)ebuf;             // 800000 dwords
    unsigned int* u2b    = (unsigned int*)(ebuf + NBUCK * BCAP); // 800000 dwords

    k_detect  <<<1, 256, 0, stream>>>(ei, W1, meta, bucket_cursor, W1f);
    k_bscatter<<<(N_EDGES + EPB - 1) / EPB, 512, 0, stream>>>(ei, meta, bucket_cursor, ebuf);
    k_bfill2  <<<NBUCK, 512, 0, stream>>>(ebuf, bucket_cursor, row_ptr, dinv, col_idx);

    k_gemm1m<<<(N_NODES + 63) / 64, 256, 0, stream>>>(x, W1f, dinv, u1q);
    k_pull1f<<<N_NODES / P_NODES, 256, 0, stream>>>(row_ptr, col_idx, dinv, u1q, b1, W2, u2b);
    k_pull2f<<<N_NODES / P_NODES, 256, 0, stream>>>(row_ptr, col_idx, dinv, u2b, b2, Wc, bc, out);
}